// Round 2
// baseline (261.335 us; speedup 1.0000x reference)
//
#include <hip/hip_runtime.h>
#include <hip/hip_bf16.h>
#include <math.h>

#define HIDDEN 1024
#define HEADS 16
#define HEAD_DIM 64
#define EPS 1e-5f

typedef __attribute__((ext_vector_type(8))) short bf16x8;
typedef __attribute__((ext_vector_type(4))) float f32x4;

#if defined(__has_builtin)
#if __has_builtin(__builtin_amdgcn_exp2f)
#define EXP2(x) __builtin_amdgcn_exp2f(x)
#endif
#endif
#ifndef EXP2
#define EXP2(x) exp2f(x)
#endif

// 0.125 (1/sqrt(64)) * log2(e): folded into Wq/bq so softmax is exp2(s)
#define QSCALE 0.18033688011112042f

__device__ __forceinline__ short f2bf(float f) {
    union { float f; unsigned u; } v; v.f = f;
    unsigned r = v.u + 0x7fffu + ((v.u >> 16) & 1u);   // RNE
    return (short)(r >> 16);
}

// async global->LDS DMA, 16 B per lane; dest = ldsbase + lane*16 (wave-uniform base)
__device__ __forceinline__ void gl_lds16(const void* g, void* l) {
    __builtin_amdgcn_global_load_lds(
        (const __attribute__((address_space(1))) void*)g,
        (__attribute__((address_space(3))) void*)l, 16, 0, 0);
}

// ---------------------------------------------------------------------------
// fp32 -> bf16 cast, 4 elems/thread
// ---------------------------------------------------------------------------
__global__ __launch_bounds__(256) void cast_bf16_kernel(
    const float* __restrict__ in, short* __restrict__ out, int n)
{
    int i = (blockIdx.x * 256 + threadIdx.x) * 4;
    if (i >= n) return;
    float4 v = *(const float4*)(in + i);
    short o[4] = { f2bf(v.x), f2bf(v.y), f2bf(v.z), f2bf(v.w) };
    *(uint2*)(out + i) = *(uint2*)o;
}

// ---------------------------------------------------------------------------
// All 4 weights: W[K,N] fp32 -> Wt[N,K] bf16 (32x32 tiles), z picks weight
// ---------------------------------------------------------------------------
__global__ __launch_bounds__(256) void wtrans_kernel(
    const float* __restrict__ Wq, const float* __restrict__ Wk,
    const float* __restrict__ Wv, const float* __restrict__ Wo,
    short* __restrict__ Wt3, short* __restrict__ Wot)
{
    const int wsel = blockIdx.z;
    const float* W = (wsel == 0) ? Wq : (wsel == 1) ? Wk : (wsel == 2) ? Wv : Wo;
    short* dst = (wsel < 3) ? (Wt3 + (size_t)wsel * 1024 * 1024) : Wot;
    const float scale = (wsel == 0) ? QSCALE : 1.0f;

    __shared__ short tile[32][33];
    int n0 = blockIdx.x * 32;
    int k0 = blockIdx.y * 32;
    int tx = threadIdx.x & 31;
    int ty = threadIdx.x >> 5;  // 0..7
    #pragma unroll
    for (int i = 0; i < 32; i += 8)
        tile[ty + i][tx] = f2bf(W[(size_t)(k0 + ty + i) * 1024 + n0 + tx] * scale);
    __syncthreads();
    #pragma unroll
    for (int i = 0; i < 32; i += 8)
        dst[(size_t)(n0 + ty + i) * 1024 + k0 + tx] = tile[tx][ty + i];
}

// ---------------------------------------------------------------------------
// b3 = concat(bq*qscale, bk, bv)
// ---------------------------------------------------------------------------
__global__ __launch_bounds__(256) void concat_bias_kernel(
    const float* __restrict__ bq, const float* __restrict__ bk,
    const float* __restrict__ bv, float* __restrict__ b3)
{
    int i = blockIdx.x * 256 + threadIdx.x;
    if (i >= 3072) return;
    float v = (i < 1024) ? bq[i] * QSCALE
            : (i < 2048) ? bk[i - 1024] : bv[i - 2048];
    b3[i] = v;
}

// ---------------------------------------------------------------------------
// C[M,N] = A[M,K] @ Bt[N,K]^T + bias[col] (+ resid fp32 if given).
// 128x128 tile, BK=32, 4 waves. Staging via global_load_lds (16B DMA),
// XOR-swizzled source columns so LDS is unpadded yet fragment reads are
// bank-balanced. Columns >= split_col go to C1 (rebased), else C0.
// ---------------------------------------------------------------------------
__global__ __launch_bounds__(256) void gemm_bt_mfma(
    const short* __restrict__ A, const short* __restrict__ Bt,
    const float* __restrict__ bias,
    void* __restrict__ C0, int ldc0,
    void* __restrict__ C1, int split_col, int ldc1,
    const float* __restrict__ resid,
    int M, int N, int K, int out_bf16)
{
    __shared__ short As[128 * 32];
    __shared__ short Bs[128 * 32];
    const int tid = threadIdx.x;
    const int wave = tid >> 6, lane = tid & 63;
    const int ln16 = lane & 15, quad = lane >> 4;
    const int wm = (wave >> 1) * 64, wn = (wave & 1) * 64;
    const int brow = blockIdx.y * 128, bcol = blockIdx.x * 128;

    const int sr  = lane >> 2;   // 0..15 row within 16-row chunk
    const int scb = lane & 3;    // lds col-block (8 shorts)

    f32x4 acc[4][4];
    #pragma unroll
    for (int mt = 0; mt < 4; ++mt)
        #pragma unroll
        for (int nt = 0; nt < 4; ++nt) acc[mt][nt] = (f32x4){0.f, 0.f, 0.f, 0.f};

    for (int k0 = 0; k0 < K; k0 += 32) {
        __syncthreads();
        #pragma unroll
        for (int i = 0; i < 2; ++i) {
            int rb = i * 64 + wave * 16;          // chunk base row (wave-uniform)
            int r  = rb + sr;
            int csrc = (scb ^ ((r >> 1) & 3)) * 8;
            gl_lds16(A  + (size_t)(brow + r) * K + k0 + csrc, &As[rb * 32]);
            gl_lds16(Bt + (size_t)(bcol + r) * K + k0 + csrc, &Bs[rb * 32]);
        }
        __syncthreads();

        bf16x8 af[4], bf[4];
        #pragma unroll
        for (int mt = 0; mt < 4; ++mt) {
            int r = wm + mt * 16 + ln16;
            af[mt] = *(const bf16x8*)&As[r * 32 + ((quad ^ ((r >> 1) & 3)) * 8)];
        }
        #pragma unroll
        for (int nt = 0; nt < 4; ++nt) {
            int r = wn + nt * 16 + ln16;
            bf[nt] = *(const bf16x8*)&Bs[r * 32 + ((quad ^ ((r >> 1) & 3)) * 8)];
        }
        #pragma unroll
        for (int mt = 0; mt < 4; ++mt)
            #pragma unroll
            for (int nt = 0; nt < 4; ++nt)
                acc[mt][nt] = __builtin_amdgcn_mfma_f32_16x16x32_bf16(
                    af[mt], bf[nt], acc[mt][nt], 0, 0, 0);
    }

    void* Cp = C0; int ld = ldc0; int coff = 0;
    if (bcol >= split_col) { Cp = C1; ld = ldc1; coff = split_col; }

    #pragma unroll
    for (int mt = 0; mt < 4; ++mt) {
        #pragma unroll
        for (int r = 0; r < 4; ++r) {
            int row = brow + wm + mt * 16 + quad * 4 + r;
            #pragma unroll
            for (int nt = 0; nt < 4; ++nt) {
                int col = bcol + wn + nt * 16 + ln16;
                float v = acc[mt][nt][r] + bias[col];
                if (resid) v += resid[(size_t)row * N + col];
                if (out_bf16) ((short*)Cp)[(size_t)row * ld + (col - coff)] = f2bf(v);
                else          ((float*)Cp)[(size_t)row * ld + (col - coff)] = v;
            }
        }
    }
}

// ---------------------------------------------------------------------------
// Vb[4096][1024] bf16 -> VT[1024][4096] bf16, 64x64 tiles
// ---------------------------------------------------------------------------
__global__ __launch_bounds__(256) void vtranspose_kernel(
    const short* __restrict__ Vb, short* __restrict__ VT)
{
    __shared__ short t[64][72];
    const int c0 = blockIdx.x * 64;    // feature block
    const int r0 = blockIdx.y * 64;    // token block
    const int tid = threadIdx.x;
    #pragma unroll
    for (int i = 0; i < 2; ++i) {
        int idx = tid + i * 256;
        int r = idx >> 3, cc = (idx & 7) * 8;
        *(uint4*)&t[r][cc] = *(const uint4*)(Vb + (size_t)(r0 + r) * 1024 + c0 + cc);
    }
    __syncthreads();
    #pragma unroll
    for (int i = 0; i < 2; ++i) {
        int idx = tid + i * 256;
        int c = idx >> 3, rr = (idx & 7) * 8;
        short tmp[8];
        #pragma unroll
        for (int j = 0; j < 8; ++j) tmp[j] = t[rr + j][c];
        *(uint4*)(VT + (size_t)(c0 + c) * 4096 + r0 + rr) = *(uint4*)tmp;
    }
}

// ---------------------------------------------------------------------------
// MFMA flash attention, k-split / zero-staging version.
// QKb[4096][2048]: Q cols 0..1023, K cols 1024..2047.  VT[1024][4096] = V^T.
// Block = (h, qt, b): 64 q-rows, 4 waves.  Wave w owns k-tokens
// [w*512, (w+1)*512) for ALL 64 q-rows: K/V fragments are loaded DIRECTLY
// from global (L2-resident: 2 heads x 2 batches per XCD = 2 MB < 4 MB L2,
// preserved by the h-major grid).  No LDS staging, no barriers in the main
// loop -- waves free-run, L2 latency hides across 12 waves/CU.  LDS is used
// only for the wave-private P transpose round-trip (16B-block XOR swizzle,
// conflict-free) and the 4-wave O / rowsum reduction in the epilogue.
// Fixed-max softmax (p = exp2(s); scale pre-folded into Wq/bq).
// ---------------------------------------------------------------------------
__global__ __launch_bounds__(256, 3) void attn_mfma_kernel(
    const short* __restrict__ QKb, const short* __restrict__ VT,
    short* __restrict__ Ctx)
{
    const int S = 2048;
    const int h = blockIdx.x, qt = blockIdx.y, b = blockIdx.z;
    const int tid = threadIdx.x;
    const int wave = tid >> 6, lane = tid & 63;
    const int ln16 = lane & 15, quad = lane >> 4;

    // smem: main loop: 4 x 4096 B wave-private P regions ([64 q][32 k] bf16,
    //       64 B pitch, 16B-block XOR swizzle).  Epilogue (after barrier):
    //       4 x 4864 B O-partial regions ([64][19] f32) + 1024 B rowsums.
    __shared__ alignas(16) char smem[20480];
    char* Pw = smem + wave * 4096;

    // Q fragments for all 64 q-rows (B-operand), straight from global
    bf16x8 qf[4][2];
    #pragma unroll
    for (int qg = 0; qg < 4; ++qg)
        #pragma unroll
        for (int kb = 0; kb < 2; ++kb)
            qf[qg][kb] = *(const bf16x8*)(QKb +
                (size_t)(b * S + qt * 64 + qg * 16 + ln16) * 2048 +
                h * 64 + kb * 32 + quad * 8);

    bf16x8 ones;
    #pragma unroll
    for (int j = 0; j < 8; ++j) ones[j] = (short)0x3F80;  // bf16 1.0

    f32x4 of[4][4], lacc[4];
    #pragma unroll
    for (int qg = 0; qg < 4; ++qg) {
        lacc[qg] = (f32x4){0.f, 0.f, 0.f, 0.f};
        #pragma unroll
        for (int nt = 0; nt < 4; ++nt) of[qg][nt] = (f32x4){0.f, 0.f, 0.f, 0.f};
    }

    const short* Kbase = QKb + (size_t)b * S * 2048 + 1024 + h * 64;
    const short* Vbase = VT + (size_t)(h * 64) * 4096 + (size_t)b * S;

    #pragma unroll 1
    for (int it = 0; it < 16; ++it) {
        const int t0 = wave * 512 + it * 32;     // this wave's 32-token window

        // ---- S^T = K Q^T for two 16-token halves; exp2; swizzled b64 P write
        #pragma unroll
        for (int kblk = 0; kblk < 2; ++kblk) {
            const short* krow = Kbase + (size_t)(t0 + kblk * 16 + ln16) * 2048;
            bf16x8 kf0 = *(const bf16x8*)(krow + quad * 8);
            bf16x8 kf1 = *(const bf16x8*)(krow + 32 + quad * 8);
            #pragma unroll
            for (int qg = 0; qg < 4; ++qg) {
                f32x4 a = (f32x4){0.f, 0.f, 0.f, 0.f};
                a = __builtin_amdgcn_mfma_f32_16x16x32_bf16(kf0, qf[qg][0], a, 0, 0, 0);
                a = __builtin_amdgcn_mfma_f32_16x16x32_bf16(kf1, qf[qg][1], a, 0, 0, 0);
                float p0 = EXP2(a[0]), p1 = EXP2(a[1]);
                float p2 = EXP2(a[2]), p3 = EXP2(a[3]);
                union { __hip_bfloat162 h2; unsigned u; } c01, c23;
                c01.h2 = __float22bfloat162_rn(make_float2(p0, p1));
                c23.h2 = __float22bfloat162_rn(make_float2(p2, p3));
                uint2 w; w.x = c01.u; w.y = c23.u;
                int row = qg * 16 + ln16;
                int blk = (kblk * 2 + (quad >> 1)) ^ (row & 3);
                *(uint2*)(Pw + row * 64 + blk * 16 + (quad & 1) * 8) = w;
            }
        }

        // ---- P fragments back (wave-private: no barrier), rowsum + PV
        bf16x8 pf[4];
        #pragma unroll
        for (int qg = 0; qg < 4; ++qg) {
            int row = qg * 16 + ln16;
            int blk = quad ^ (row & 3);
            pf[qg] = *(const bf16x8*)(Pw + row * 64 + blk * 16);
            lacc[qg] = __builtin_amdgcn_mfma_f32_16x16x32_bf16(pf[qg], ones, lacc[qg], 0, 0, 0);
        }
        #pragma unroll
        for (int nt = 0; nt < 4; ++nt) {
            bf16x8 vf = *(const bf16x8*)(Vbase + (size_t)(nt * 16 + ln16) * 4096 + t0 + quad * 8);
            #pragma unroll
            for (int qg = 0; qg < 4; ++qg)
                of[qg][nt] = __builtin_amdgcn_mfma_f32_16x16x32_bf16(pf[qg], vf, of[qg][nt], 0, 0, 0);
        }
    }

    // ---- epilogue: cross-wave reduce of O partials and rowsums
    __syncthreads();                              // P regions dead; smem reused

    float* Rw = (float*)(smem + wave * 4864);     // [64][19] f32, this wave
    float* Lb = (float*)(smem + 4 * 4864);        // [4][64] rowsum partials

    if (ln16 == 0) {
        #pragma unroll
        for (int qg = 0; qg < 4; ++qg)
            #pragma unroll
            for (int r = 0; r < 4; ++r)
                Lb[wave * 64 + qg * 16 + quad * 4 + r] = lacc[qg][r];
    }

    const int rq  = tid >> 2;          // 0..63: q-row this thread reduces
    const int rd0 = (tid & 3) * 4;     // 4 d-cols per thread
    float inv = 0.f;

    #pragma unroll
    for (int nt = 0; nt < 4; ++nt) {
        #pragma unroll
        for (int qg = 0; qg < 4; ++qg)
            #pragma unroll
            for (int r = 0; r < 4; ++r)
                Rw[(qg * 16 + quad * 4 + r) * 19 + ln16] = of[qg][nt][r];
        __syncthreads();
        if (nt == 0) {
            float l = Lb[rq] + Lb[64 + rq] + Lb[128 + rq] + Lb[192 + rq];
            inv = 1.f / l;
        }
        short o4[4];
        #pragma unroll
        for (int j = 0; j < 4; ++j) {
            int d = rd0 + j;
            float s = 0.f;
            #pragma unroll
            for (int w = 0; w < 4; ++w)
                s += ((const float*)(smem + w * 4864))[rq * 19 + d];
            o4[j] = f2bf(s * inv);
        }
        *(uint2*)(Ctx + (size_t)(b * S + qt * 64 + rq) * 1024 + h * 64 + nt * 16 + rd0) =
            *(uint2*)o4;
        __syncthreads();
    }
}

// ---------------------------------------------------------------------------
// out = LayerNorm(x) * gamma + beta (residual already folded into x).
// One block per row; exactly one float4 per thread.
// ---------------------------------------------------------------------------
__global__ __launch_bounds__(256) void resln_kernel(
    const float* __restrict__ xin, const float* __restrict__ gamma,
    const float* __restrict__ beta, float* __restrict__ out)
{
    const int row = blockIdx.x;
    const int tid = threadIdx.x;
    const int wid = tid >> 6, lane = tid & 63;
    __shared__ float red[8];

    float4 x = *(const float4*)(xin + (size_t)row * HIDDEN + tid * 4);
    float s = x.x + x.y + x.z + x.w;
    #pragma unroll
    for (int off = 32; off > 0; off >>= 1) s += __shfl_xor(s, off, 64);
    if (lane == 0) red[wid] = s;
    __syncthreads();
    float mu = (red[0] + red[1] + red[2] + red[3]) * (1.f / HIDDEN);

    float dx = x.x - mu, dy = x.y - mu, dz = x.z - mu, dw = x.w - mu;
    float v = dx * dx + dy * dy + dz * dz + dw * dw;
    #pragma unroll
    for (int off = 32; off > 0; off >>= 1) v += __shfl_xor(v, off, 64);
    if (lane == 0) red[4 + wid] = v;
    __syncthreads();
    float var = (red[4] + red[5] + red[6] + red[7]) * (1.f / HIDDEN);
    float rstd = rsqrtf(var + EPS);

    float4 g = *(const float4*)(gamma + tid * 4);
    float4 bt = *(const float4*)(beta + tid * 4);
    float4 o;
    o.x = dx * rstd * g.x + bt.x;
    o.y = dy * rstd * g.y + bt.y;
    o.z = dz * rstd * g.z + bt.z;
    o.w = dw * rstd * g.w + bt.w;
    *(float4*)(out + (size_t)row * HIDDEN + tid * 4) = o;
}

// ---------------------------------------------------------------------------
extern "C" void kernel_launch(void* const* d_in, const int* in_sizes, int n_in,
                              void* d_out, int out_size, void* d_ws, size_t ws_size,
                              hipStream_t stream)
{
    const float* X     = (const float*)d_in[0];
    const float* Wq    = (const float*)d_in[1];
    const float* bq    = (const float*)d_in[2];
    const float* Wk    = (const float*)d_in[3];
    const float* bk    = (const float*)d_in[4];
    const float* Wv    = (const float*)d_in[5];
    const float* bv    = (const float*)d_in[6];
    const float* Wo    = (const float*)d_in[7];
    const float* bo    = (const float*)d_in[8];
    const float* gamma = (const float*)d_in[9];
    const float* beta  = (const float*)d_in[10];
    float* out = (float*)d_out;

    const int B = 2, S = 2048;
    const int M = B * S;                       // 4096
    const size_t mat = (size_t)M * HIDDEN;     // 4M elems

    // workspace map (peak 41 MB):
    //   [0,8)    Xb (dead after QKV gemm) -> VT overlays
    //   [8,10)   Wot
    //   [10,16)  Wt3 (3072x1024 bf16)
    //   [16,17)  b3
    //   [17,33)  QKb (dead after attn) -> Pj (fp32) overlays
    //   [33,41)  Vb (dead after vtrans) -> Ctx overlays
    char* ws = (char*)d_ws;
    short* Xb  = (short*)(ws);
    short* VT  = (short*)(ws);
    short* Wot = (short*)(ws + (8ull << 20));
    short* Wt3 = (short*)(ws + (10ull << 20));
    float* b3  = (float*)(ws + (16ull << 20));
    short* QKb = (short*)(ws + (17ull << 20));
    float* Pj  = (float*)(ws + (17ull << 20));
    short* Vb  = (short*)(ws + (33ull << 20));
    short* Ctx = (short*)(ws + (33ull << 20));

    dim3 blk(256);

    cast_bf16_kernel<<<dim3((int)(mat / 4 / 256)), blk, 0, stream>>>(X, Xb, (int)mat);
    wtrans_kernel<<<dim3(32, 32, 4), blk, 0, stream>>>(Wq, Wk, Wv, Wo, Wt3, Wot);
    concat_bias_kernel<<<12, blk, 0, stream>>>(bq, bk, bv, b3);

    // fused QKV projection: N=3072, V columns routed to Vb
    dim3 qkvgrid(3072 / 128, M / 128);         // (24, 32) = 768 blocks
    gemm_bt_mfma<<<qkvgrid, blk, 0, stream>>>(Xb, Wt3, b3,
                                              QKb, 2048, Vb, 2048, 1024,
                                              nullptr, M, 3072, HIDDEN, 1);

    vtranspose_kernel<<<dim3(16, 64), blk, 0, stream>>>(Vb, VT);

    dim3 agrid(HEADS, S / 64, B);              // (16, 32, 2) = 1024 blocks
    attn_mfma_kernel<<<agrid, blk, 0, stream>>>(QKb, VT, Ctx);

    // output projection + bias + residual (fp32 out)
    dim3 ogrid(HIDDEN / 128, M / 128);         // (8, 32)
    gemm_bt_mfma<<<ogrid, blk, 0, stream>>>(Ctx, Wot, bo,
                                            Pj, 1024, nullptr, 1 << 30, 0,
                                            X, M, HIDDEN, HIDDEN, 0);

    resln_kernel<<<M, blk, 0, stream>>>(Pj, gamma, beta, out);
}

// Round 3
// 250.611 us; speedup vs baseline: 1.0428x; 1.0428x over previous
//
#include <hip/hip_runtime.h>
#include <hip/hip_bf16.h>
#include <math.h>

#define HIDDEN 1024
#define HEADS 16
#define HEAD_DIM 64
#define EPS 1e-5f

typedef __attribute__((ext_vector_type(8))) short bf16x8;
typedef __attribute__((ext_vector_type(4))) float f32x4;

#if defined(__has_builtin)
#if __has_builtin(__builtin_amdgcn_exp2f)
#define EXP2(x) __builtin_amdgcn_exp2f(x)
#endif
#endif
#ifndef EXP2
#define EXP2(x) exp2f(x)
#endif

// 0.125 (1/sqrt(64)) * log2(e): folded into Wq/bq so softmax is exp2(s)
#define QSCALE 0.18033688011112042f

__device__ __forceinline__ short f2bf(float f) {
    union { float f; unsigned u; } v; v.f = f;
    unsigned r = v.u + 0x7fffu + ((v.u >> 16) & 1u);   // RNE
    return (short)(r >> 16);
}

// async global->LDS DMA, 16 B per lane; dest = ldsbase + lane*16 (wave-uniform base)
__device__ __forceinline__ void gl_lds16(const void* g, void* l) {
    __builtin_amdgcn_global_load_lds(
        (const __attribute__((address_space(1))) void*)g,
        (__attribute__((address_space(3))) void*)l, 16, 0, 0);
}

// ---------------------------------------------------------------------------
// fp32 -> bf16 cast, 4 elems/thread
// ---------------------------------------------------------------------------
__global__ __launch_bounds__(256) void cast_bf16_kernel(
    const float* __restrict__ in, short* __restrict__ out, int n)
{
    int i = (blockIdx.x * 256 + threadIdx.x) * 4;
    if (i >= n) return;
    float4 v = *(const float4*)(in + i);
    short o[4] = { f2bf(v.x), f2bf(v.y), f2bf(v.z), f2bf(v.w) };
    *(uint2*)(out + i) = *(uint2*)o;
}

// ---------------------------------------------------------------------------
// All 4 weights: W[K,N] fp32 -> Wt[N,K] bf16 (32x32 tiles), z picks weight
// ---------------------------------------------------------------------------
__global__ __launch_bounds__(256) void wtrans_kernel(
    const float* __restrict__ Wq, const float* __restrict__ Wk,
    const float* __restrict__ Wv, const float* __restrict__ Wo,
    short* __restrict__ Wt3, short* __restrict__ Wot)
{
    const int wsel = blockIdx.z;
    const float* W = (wsel == 0) ? Wq : (wsel == 1) ? Wk : (wsel == 2) ? Wv : Wo;
    short* dst = (wsel < 3) ? (Wt3 + (size_t)wsel * 1024 * 1024) : Wot;
    const float scale = (wsel == 0) ? QSCALE : 1.0f;

    __shared__ short tile[32][33];
    int n0 = blockIdx.x * 32;
    int k0 = blockIdx.y * 32;
    int tx = threadIdx.x & 31;
    int ty = threadIdx.x >> 5;  // 0..7
    #pragma unroll
    for (int i = 0; i < 32; i += 8)
        tile[ty + i][tx] = f2bf(W[(size_t)(k0 + ty + i) * 1024 + n0 + tx] * scale);
    __syncthreads();
    #pragma unroll
    for (int i = 0; i < 32; i += 8)
        dst[(size_t)(n0 + ty + i) * 1024 + k0 + tx] = tile[tx][ty + i];
}

// ---------------------------------------------------------------------------
// b3 = concat(bq*qscale, bk, bv)
// ---------------------------------------------------------------------------
__global__ __launch_bounds__(256) void concat_bias_kernel(
    const float* __restrict__ bq, const float* __restrict__ bk,
    const float* __restrict__ bv, float* __restrict__ b3)
{
    int i = blockIdx.x * 256 + threadIdx.x;
    if (i >= 3072) return;
    float v = (i < 1024) ? bq[i] * QSCALE
            : (i < 2048) ? bk[i - 1024] : bv[i - 2048];
    b3[i] = v;
}

// ---------------------------------------------------------------------------
// C[M,N] = A[M,K] @ Bt[N,K]^T + bias[col] (+ resid fp32 if given).
// 128x128 tile, BK=32, 4 waves. Staging via global_load_lds (16B DMA),
// XOR-swizzled source columns so LDS is unpadded yet fragment reads are
// bank-balanced. Columns >= split_col go to C1 (rebased), else C0.
// ---------------------------------------------------------------------------
__global__ __launch_bounds__(256) void gemm_bt_mfma(
    const short* __restrict__ A, const short* __restrict__ Bt,
    const float* __restrict__ bias,
    void* __restrict__ C0, int ldc0,
    void* __restrict__ C1, int split_col, int ldc1,
    const float* __restrict__ resid,
    int M, int N, int K, int out_bf16)
{
    __shared__ short As[128 * 32];
    __shared__ short Bs[128 * 32];
    const int tid = threadIdx.x;
    const int wave = tid >> 6, lane = tid & 63;
    const int ln16 = lane & 15, quad = lane >> 4;
    const int wm = (wave >> 1) * 64, wn = (wave & 1) * 64;
    const int brow = blockIdx.y * 128, bcol = blockIdx.x * 128;

    const int sr  = lane >> 2;   // 0..15 row within 16-row chunk
    const int scb = lane & 3;    // lds col-block (8 shorts)

    f32x4 acc[4][4];
    #pragma unroll
    for (int mt = 0; mt < 4; ++mt)
        #pragma unroll
        for (int nt = 0; nt < 4; ++nt) acc[mt][nt] = (f32x4){0.f, 0.f, 0.f, 0.f};

    for (int k0 = 0; k0 < K; k0 += 32) {
        __syncthreads();
        #pragma unroll
        for (int i = 0; i < 2; ++i) {
            int rb = i * 64 + wave * 16;          // chunk base row (wave-uniform)
            int r  = rb + sr;
            int csrc = (scb ^ ((r >> 1) & 3)) * 8;
            gl_lds16(A  + (size_t)(brow + r) * K + k0 + csrc, &As[rb * 32]);
            gl_lds16(Bt + (size_t)(bcol + r) * K + k0 + csrc, &Bs[rb * 32]);
        }
        __syncthreads();

        bf16x8 af[4], bf[4];
        #pragma unroll
        for (int mt = 0; mt < 4; ++mt) {
            int r = wm + mt * 16 + ln16;
            af[mt] = *(const bf16x8*)&As[r * 32 + ((quad ^ ((r >> 1) & 3)) * 8)];
        }
        #pragma unroll
        for (int nt = 0; nt < 4; ++nt) {
            int r = wn + nt * 16 + ln16;
            bf[nt] = *(const bf16x8*)&Bs[r * 32 + ((quad ^ ((r >> 1) & 3)) * 8)];
        }
        #pragma unroll
        for (int mt = 0; mt < 4; ++mt)
            #pragma unroll
            for (int nt = 0; nt < 4; ++nt)
                acc[mt][nt] = __builtin_amdgcn_mfma_f32_16x16x32_bf16(
                    af[mt], bf[nt], acc[mt][nt], 0, 0, 0);
    }

    void* Cp = C0; int ld = ldc0; int coff = 0;
    if (bcol >= split_col) { Cp = C1; ld = ldc1; coff = split_col; }

    #pragma unroll
    for (int mt = 0; mt < 4; ++mt) {
        #pragma unroll
        for (int r = 0; r < 4; ++r) {
            int row = brow + wm + mt * 16 + quad * 4 + r;
            #pragma unroll
            for (int nt = 0; nt < 4; ++nt) {
                int col = bcol + wn + nt * 16 + ln16;
                float v = acc[mt][nt][r] + bias[col];
                if (resid) v += resid[(size_t)row * N + col];
                if (out_bf16) ((short*)Cp)[(size_t)row * ld + (col - coff)] = f2bf(v);
                else          ((float*)Cp)[(size_t)row * ld + (col - coff)] = v;
            }
        }
    }
}

// ---------------------------------------------------------------------------
// Vb[4096][1024] bf16 -> VT[1024][4096] bf16, 64x64 tiles
// ---------------------------------------------------------------------------
__global__ __launch_bounds__(256) void vtranspose_kernel(
    const short* __restrict__ Vb, short* __restrict__ VT)
{
    __shared__ short t[64][72];
    const int c0 = blockIdx.x * 64;    // feature block
    const int r0 = blockIdx.y * 64;    // token block
    const int tid = threadIdx.x;
    #pragma unroll
    for (int i = 0; i < 2; ++i) {
        int idx = tid + i * 256;
        int r = idx >> 3, cc = (idx & 7) * 8;
        *(uint4*)&t[r][cc] = *(const uint4*)(Vb + (size_t)(r0 + r) * 1024 + c0 + cc);
    }
    __syncthreads();
    #pragma unroll
    for (int i = 0; i < 2; ++i) {
        int idx = tid + i * 256;
        int c = idx >> 3, rr = (idx & 7) * 8;
        short tmp[8];
        #pragma unroll
        for (int j = 0; j < 8; ++j) tmp[j] = t[rr + j][c];
        *(uint4*)(VT + (size_t)(c0 + c) * 4096 + r0 + rr) = *(uint4*)tmp;
    }
}

// ---------------------------------------------------------------------------
// MFMA flash attention: LDS-staged tiles + k-split across waves.
// QKb[4096][2048]: Q cols 0..1023, K cols 1024..2047.  VT[1024][4096] = V^T.
// Block = (h, qt, b): 64 q-rows, 4 waves, 128-token k-tiles (16 iters).
// Wave w owns tokens [32w, 32w+32) of each tile for ALL 64 q-rows ->
// each wave reads only 1/4 of the K/V tile from LDS (vs 4x redundancy of
// the q-split layout).  K/V double-buffered via global_load_lds (coalesced
// DMA, XOR-swizzled source cols) with counted vmcnt + raw s_barriers so
// next tile's DMA flies under this tile's compute.  P round-trip is
// wave-private (no barrier), 16B-block XOR swizzle key (q>>1)&3 (full
// {0..3} coverage on even rows -- fixes the round-2 8-way write conflict).
// Cross-wave O/rowsum reduction in the epilogue (smem reused after barrier).
// Fixed-max softmax (p = exp2(s); scale pre-folded into Wq/bq).
// ---------------------------------------------------------------------------
__global__ __launch_bounds__(256, 2) void attn_mfma_kernel(
    const short* __restrict__ QKb, const short* __restrict__ VT,
    short* __restrict__ Ctx)
{
    const int S = 2048;
    const int h = blockIdx.x, qt = blockIdx.y, b = blockIdx.z;
    const int tid = threadIdx.x;
    const int wave = tid >> 6, lane = tid & 63;
    const int ln16 = lane & 15, quad = lane >> 4;

    // LDS 81920 B (2 blocks/CU):
    //   [0,32768)     Ks[2][128 tok][64 d]   rows 128 B, 16B-block key r&7
    //   [32768,65536) Vs[2][64 d][128 tok]   rows 256 B, 16B-block key d&15
    //   [65536,81920) Ps[4][64 q][32 k]      per-wave 4 KB, key (q>>1)&3
    // epilogue overlays [0,20480): Rw[4][64][19] f32 + Lb[4][64] f32
    __shared__ alignas(16) char smem[81920];
    char* Pw = smem + 65536 + wave * 4096;

    // Q fragments for all 64 q-rows (B-operand), straight from global
    bf16x8 qf[4][2];
    #pragma unroll
    for (int qg = 0; qg < 4; ++qg)
        #pragma unroll
        for (int kb = 0; kb < 2; ++kb)
            qf[qg][kb] = *(const bf16x8*)(QKb +
                (size_t)(b * S + qt * 64 + qg * 16 + ln16) * 2048 +
                h * 64 + kb * 32 + quad * 8);

    bf16x8 ones;
    #pragma unroll
    for (int j = 0; j < 8; ++j) ones[j] = (short)0x3F80;  // bf16 1.0

    f32x4 of[4][4], lacc[4];
    #pragma unroll
    for (int qg = 0; qg < 4; ++qg) {
        lacc[qg] = (f32x4){0.f, 0.f, 0.f, 0.f};
        #pragma unroll
        for (int nt = 0; nt < 4; ++nt) of[qg][nt] = (f32x4){0.f, 0.f, 0.f, 0.f};
    }

    // stage 128-token tile kt into buffer p: 8 DMA per wave
    // (wave stages K rows [32w,32w+32) and V feature-rows [16w,16w+16))
    auto stage = [&](int p, int kt) {
        short* ksb = (short*)(smem + p * 16384);
        short* vsb = (short*)(smem + 32768 + p * 16384);
        const int kr  = lane >> 3;    // 0..7  row within 8-row K chunk
        const int kb8 = lane & 7;     // K 16B-block in 128-B row
        const int vr  = lane >> 4;    // 0..3  row within 4-row V chunk
        const int vb16 = lane & 15;   // V 16B-block in 256-B row
        #pragma unroll
        for (int i = 0; i < 4; ++i) {
            int r = wave * 32 + i * 8 + kr;               // tile token row
            int ksrc = (kb8 ^ (r & 7)) * 8;
            gl_lds16(QKb + (size_t)(b * S + kt * 128 + r) * 2048 + 1024 + h * 64 + ksrc,
                     ksb + (wave * 32 + i * 8) * 64);
            int d = wave * 16 + i * 4 + vr;               // feature row
            int vsrc = (vb16 ^ (d & 15)) * 8;
            gl_lds16(VT + (size_t)(h * 64 + d) * 4096 + b * S + kt * 128 + vsrc,
                     vsb + (wave * 16 + i * 4) * 128);
        }
    };

    stage(0, 0);

    for (int kt = 0; kt < 16; ++kt) {
        const int p = kt & 1;

        if (kt + 1 < 16) {
            stage(p ^ 1, kt + 1);                         // next tile in flight
            asm volatile("s_waitcnt vmcnt(8)" ::: "memory");  // prev 8 done
        } else {
            asm volatile("s_waitcnt vmcnt(0)" ::: "memory");
        }
        __builtin_amdgcn_s_barrier();                     // tile kt staged
        __builtin_amdgcn_sched_barrier(0);

        const short* ks = (const short*)(smem + p * 16384);
        const short* vs = (const short*)(smem + 32768 + p * 16384);
        const int t0w = wave * 32;                        // this wave's tokens

        // ---- S^T = K Q^T (two 16-token halves); exp2; swizzled b64 P write
        #pragma unroll
        for (int kblk = 0; kblk < 2; ++kblk) {
            int rloc = t0w + kblk * 16 + ln16;
            bf16x8 kf0 = *(const bf16x8*)&ks[rloc * 64 + ((quad ^ (rloc & 7)) * 8)];
            bf16x8 kf1 = *(const bf16x8*)&ks[rloc * 64 + (((4 + quad) ^ (rloc & 7)) * 8)];
            #pragma unroll
            for (int qg = 0; qg < 4; ++qg) {
                f32x4 a = (f32x4){0.f, 0.f, 0.f, 0.f};
                a = __builtin_amdgcn_mfma_f32_16x16x32_bf16(kf0, qf[qg][0], a, 0, 0, 0);
                a = __builtin_amdgcn_mfma_f32_16x16x32_bf16(kf1, qf[qg][1], a, 0, 0, 0);
                float p0 = EXP2(a[0]), p1 = EXP2(a[1]);
                float p2 = EXP2(a[2]), p3 = EXP2(a[3]);
                union { __hip_bfloat162 h2; unsigned u; } c01, c23;
                c01.h2 = __float22bfloat162_rn(make_float2(p0, p1));
                c23.h2 = __float22bfloat162_rn(make_float2(p2, p3));
                uint2 w; w.x = c01.u; w.y = c23.u;
                int qrow = qg * 16 + ln16;
                int key = (qrow >> 1) & 3;
                int bblk = (kblk * 2 + (quad >> 1)) ^ key;
                *(uint2*)(Pw + qrow * 64 + bblk * 16 + (quad & 1) * 8) = w;
            }
        }

        // ---- P fragments back (wave-private: no barrier), rowsum + PV
        bf16x8 pf[4];
        #pragma unroll
        for (int qg = 0; qg < 4; ++qg) {
            int qrow = qg * 16 + ln16;
            int key = (qrow >> 1) & 3;
            pf[qg] = *(const bf16x8*)(Pw + qrow * 64 + ((quad ^ key) * 16));
            lacc[qg] = __builtin_amdgcn_mfma_f32_16x16x32_bf16(pf[qg], ones, lacc[qg], 0, 0, 0);
        }
        #pragma unroll
        for (int nt = 0; nt < 4; ++nt) {
            int d = nt * 16 + ln16;
            bf16x8 vf = *(const bf16x8*)&vs[d * 128 + (((wave * 4 + quad) ^ (d & 15)) * 8)];
            #pragma unroll
            for (int qg = 0; qg < 4; ++qg)
                of[qg][nt] = __builtin_amdgcn_mfma_f32_16x16x32_bf16(pf[qg], vf, of[qg][nt], 0, 0, 0);
        }

        __builtin_amdgcn_sched_barrier(0);
        __builtin_amdgcn_s_barrier();                     // all done reading p
    }

    // ---- epilogue: cross-wave reduce of O partials and rowsums
    __syncthreads();                              // tiles dead; smem reused

    float* Rw = (float*)(smem + wave * 4864);     // [64][19] f32, this wave
    float* Lb = (float*)(smem + 4 * 4864);        // [4][64] rowsum partials

    if (ln16 == 0) {
        #pragma unroll
        for (int qg = 0; qg < 4; ++qg)
            #pragma unroll
            for (int r = 0; r < 4; ++r)
                Lb[wave * 64 + qg * 16 + quad * 4 + r] = lacc[qg][r];
    }

    const int rq  = tid >> 2;          // 0..63: q-row this thread reduces
    const int rd0 = (tid & 3) * 4;     // 4 d-cols per thread
    float inv = 0.f;

    #pragma unroll
    for (int nt = 0; nt < 4; ++nt) {
        #pragma unroll
        for (int qg = 0; qg < 4; ++qg)
            #pragma unroll
            for (int r = 0; r < 4; ++r)
                Rw[(qg * 16 + quad * 4 + r) * 19 + ln16] = of[qg][nt][r];
        __syncthreads();
        if (nt == 0) {
            float l = Lb[rq] + Lb[64 + rq] + Lb[128 + rq] + Lb[192 + rq];
            inv = 1.f / l;
        }
        short o4[4];
        #pragma unroll
        for (int j = 0; j < 4; ++j) {
            int d = rd0 + j;
            float s = 0.f;
            #pragma unroll
            for (int w = 0; w < 4; ++w)
                s += ((const float*)(smem + w * 4864))[rq * 19 + d];
            o4[j] = f2bf(s * inv);
        }
        *(uint2*)(Ctx + (size_t)(b * S + qt * 64 + rq) * 1024 + h * 64 + nt * 16 + rd0) =
            *(uint2*)o4;
        __syncthreads();
    }
}

// ---------------------------------------------------------------------------
// out = LayerNorm(x) * gamma + beta (residual already folded into x).
// One block per row; exactly one float4 per thread.
// ---------------------------------------------------------------------------
__global__ __launch_bounds__(256) void resln_kernel(
    const float* __restrict__ xin, const float* __restrict__ gamma,
    const float* __restrict__ beta, float* __restrict__ out)
{
    const int row = blockIdx.x;
    const int tid = threadIdx.x;
    const int wid = tid >> 6, lane = tid & 63;
    __shared__ float red[8];

    float4 x = *(const float4*)(xin + (size_t)row * HIDDEN + tid * 4);
    float s = x.x + x.y + x.z + x.w;
    #pragma unroll
    for (int off = 32; off > 0; off >>= 1) s += __shfl_xor(s, off, 64);
    if (lane == 0) red[wid] = s;
    __syncthreads();
    float mu = (red[0] + red[1] + red[2] + red[3]) * (1.f / HIDDEN);

    float dx = x.x - mu, dy = x.y - mu, dz = x.z - mu, dw = x.w - mu;
    float v = dx * dx + dy * dy + dz * dz + dw * dw;
    #pragma unroll
    for (int off = 32; off > 0; off >>= 1) v += __shfl_xor(v, off, 64);
    if (lane == 0) red[4 + wid] = v;
    __syncthreads();
    float var = (red[4] + red[5] + red[6] + red[7]) * (1.f / HIDDEN);
    float rstd = rsqrtf(var + EPS);

    float4 g = *(const float4*)(gamma + tid * 4);
    float4 bt = *(const float4*)(beta + tid * 4);
    float4 o;
    o.x = dx * rstd * g.x + bt.x;
    o.y = dy * rstd * g.y + bt.y;
    o.z = dz * rstd * g.z + bt.z;
    o.w = dw * rstd * g.w + bt.w;
    *(float4*)(out + (size_t)row * HIDDEN + tid * 4) = o;
}

// ---------------------------------------------------------------------------
extern "C" void kernel_launch(void* const* d_in, const int* in_sizes, int n_in,
                              void* d_out, int out_size, void* d_ws, size_t ws_size,
                              hipStream_t stream)
{
    const float* X     = (const float*)d_in[0];
    const float* Wq    = (const float*)d_in[1];
    const float* bq    = (const float*)d_in[2];
    const float* Wk    = (const float*)d_in[3];
    const float* bk    = (const float*)d_in[4];
    const float* Wv    = (const float*)d_in[5];
    const float* bv    = (const float*)d_in[6];
    const float* Wo    = (const float*)d_in[7];
    const float* bo    = (const float*)d_in[8];
    const float* gamma = (const float*)d_in[9];
    const float* beta  = (const float*)d_in[10];
    float* out = (float*)d_out;

    const int B = 2, S = 2048;
    const int M = B * S;                       // 4096
    const size_t mat = (size_t)M * HIDDEN;     // 4M elems

    // workspace map (peak 41 MB):
    //   [0,8)    Xb (dead after QKV gemm) -> VT overlays
    //   [8,10)   Wot
    //   [10,16)  Wt3 (3072x1024 bf16)
    //   [16,17)  b3
    //   [17,33)  QKb (dead after attn) -> Pj (fp32) overlays
    //   [33,41)  Vb (dead after vtrans) -> Ctx overlays
    char* ws = (char*)d_ws;
    short* Xb  = (short*)(ws);
    short* VT  = (short*)(ws);
    short* Wot = (short*)(ws + (8ull << 20));
    short* Wt3 = (short*)(ws + (10ull << 20));
    float* b3  = (float*)(ws + (16ull << 20));
    short* QKb = (short*)(ws + (17ull << 20));
    float* Pj  = (float*)(ws + (17ull << 20));
    short* Vb  = (short*)(ws + (33ull << 20));
    short* Ctx = (short*)(ws + (33ull << 20));

    dim3 blk(256);

    cast_bf16_kernel<<<dim3((int)(mat / 4 / 256)), blk, 0, stream>>>(X, Xb, (int)mat);
    wtrans_kernel<<<dim3(32, 32, 4), blk, 0, stream>>>(Wq, Wk, Wv, Wo, Wt3, Wot);
    concat_bias_kernel<<<12, blk, 0, stream>>>(bq, bk, bv, b3);

    // fused QKV projection: N=3072, V columns routed to Vb
    dim3 qkvgrid(3072 / 128, M / 128);         // (24, 32) = 768 blocks
    gemm_bt_mfma<<<qkvgrid, blk, 0, stream>>>(Xb, Wt3, b3,
                                              QKb, 2048, Vb, 2048, 1024,
                                              nullptr, M, 3072, HIDDEN, 1);

    vtranspose_kernel<<<dim3(16, 64), blk, 0, stream>>>(Vb, VT);

    dim3 agrid(HEADS, S / 64, B);              // (16, 32, 2) = 1024 blocks
    attn_mfma_kernel<<<agrid, blk, 0, stream>>>(QKb, VT, Ctx);

    // output projection + bias + residual (fp32 out)
    dim3 ogrid(HIDDEN / 128, M / 128);         // (8, 32)
    gemm_bt_mfma<<<ogrid, blk, 0, stream>>>(Ctx, Wot, bo,
                                            Pj, 1024, nullptr, 1 << 30, 0,
                                            X, M, HIDDEN, HIDDEN, 0);

    resln_kernel<<<M, blk, 0, stream>>>(Pj, gamma, beta, out);
}

// Round 4
// 248.033 us; speedup vs baseline: 1.0536x; 1.0104x over previous
//
#include <hip/hip_runtime.h>
#include <hip/hip_bf16.h>
#include <math.h>

#define HIDDEN 1024
#define HEADS 16
#define HEAD_DIM 64
#define EPS 1e-5f

typedef __attribute__((ext_vector_type(8))) short bf16x8;
typedef __attribute__((ext_vector_type(4))) float f32x4;

#if defined(__has_builtin)
#if __has_builtin(__builtin_amdgcn_exp2f)
#define EXP2(x) __builtin_amdgcn_exp2f(x)
#endif
#endif
#ifndef EXP2
#define EXP2(x) exp2f(x)
#endif

// 0.125 (1/sqrt(64)) * log2(e): folded into Wq/bq so softmax is exp2(s)
#define QSCALE 0.18033688011112042f

__device__ __forceinline__ short f2bf(float f) {
    union { float f; unsigned u; } v; v.f = f;
    unsigned r = v.u + 0x7fffu + ((v.u >> 16) & 1u);   // RNE
    return (short)(r >> 16);
}

// async global->LDS DMA, 16 B per lane; dest = ldsbase + lane*16 (wave-uniform base)
__device__ __forceinline__ void gl_lds16(const void* g, void* l) {
    __builtin_amdgcn_global_load_lds(
        (const __attribute__((address_space(1))) void*)g,
        (__attribute__((address_space(3))) void*)l, 16, 0, 0);
}

// ---------------------------------------------------------------------------
// fp32 -> bf16 cast, 4 elems/thread
// ---------------------------------------------------------------------------
__global__ __launch_bounds__(256) void cast_bf16_kernel(
    const float* __restrict__ in, short* __restrict__ out, int n)
{
    int i = (blockIdx.x * 256 + threadIdx.x) * 4;
    if (i >= n) return;
    float4 v = *(const float4*)(in + i);
    short o[4] = { f2bf(v.x), f2bf(v.y), f2bf(v.z), f2bf(v.w) };
    *(uint2*)(out + i) = *(uint2*)o;
}

// ---------------------------------------------------------------------------
// All 4 weights: W[K,N] fp32 -> Wt[N,K] bf16 (32x32 tiles), z picks weight
// ---------------------------------------------------------------------------
__global__ __launch_bounds__(256) void wtrans_kernel(
    const float* __restrict__ Wq, const float* __restrict__ Wk,
    const float* __restrict__ Wv, const float* __restrict__ Wo,
    short* __restrict__ Wt3, short* __restrict__ Wot)
{
    const int wsel = blockIdx.z;
    const float* W = (wsel == 0) ? Wq : (wsel == 1) ? Wk : (wsel == 2) ? Wv : Wo;
    short* dst = (wsel < 3) ? (Wt3 + (size_t)wsel * 1024 * 1024) : Wot;
    const float scale = (wsel == 0) ? QSCALE : 1.0f;

    __shared__ short tile[32][33];
    int n0 = blockIdx.x * 32;
    int k0 = blockIdx.y * 32;
    int tx = threadIdx.x & 31;
    int ty = threadIdx.x >> 5;  // 0..7
    #pragma unroll
    for (int i = 0; i < 32; i += 8)
        tile[ty + i][tx] = f2bf(W[(size_t)(k0 + ty + i) * 1024 + n0 + tx] * scale);
    __syncthreads();
    #pragma unroll
    for (int i = 0; i < 32; i += 8)
        dst[(size_t)(n0 + ty + i) * 1024 + k0 + tx] = tile[tx][ty + i];
}

// ---------------------------------------------------------------------------
// b3 = concat(bq*qscale, bk, bv)
// ---------------------------------------------------------------------------
__global__ __launch_bounds__(256) void concat_bias_kernel(
    const float* __restrict__ bq, const float* __restrict__ bk,
    const float* __restrict__ bv, float* __restrict__ b3)
{
    int i = blockIdx.x * 256 + threadIdx.x;
    if (i >= 3072) return;
    float v = (i < 1024) ? bq[i] * QSCALE
            : (i < 2048) ? bk[i - 1024] : bv[i - 2048];
    b3[i] = v;
}

// ---------------------------------------------------------------------------
// C[M,N] = A[M,K] @ Bt[N,K]^T + bias[col] (+ resid fp32 if given).
// 128x128 tile, BK=32, 4 waves. Staging via global_load_lds (16B DMA),
// XOR-swizzled source columns so LDS is unpadded yet fragment reads are
// bank-balanced. Columns >= split_col go to C1 (rebased), else C0.
// Bijective XCD swizzle (nwg%8==0 for both call sites) so each XCD's L2
// keeps a contiguous row-chunk of output tiles (A-panel reuse).
// ---------------------------------------------------------------------------
__global__ __launch_bounds__(256) void gemm_bt_mfma(
    const short* __restrict__ A, const short* __restrict__ Bt,
    const float* __restrict__ bias,
    void* __restrict__ C0, int ldc0,
    void* __restrict__ C1, int split_col, int ldc1,
    const float* __restrict__ resid,
    int M, int N, int K, int out_bf16)
{
    __shared__ short As[128 * 32];
    __shared__ short Bs[128 * 32];
    const int tid = threadIdx.x;
    const int wave = tid >> 6, lane = tid & 63;
    const int ln16 = lane & 15, quad = lane >> 4;
    const int wm = (wave >> 1) * 64, wn = (wave & 1) * 64;

    const int gx = gridDim.x;
    int bid = blockIdx.y * gx + blockIdx.x;
    const int cpx = (gx * gridDim.y) >> 3;     // nwg/8, exact (768, 256)
    bid = (bid & 7) * cpx + (bid >> 3);        // XCD-contiguous logical tiles
    const int brow = (bid / gx) * 128, bcol = (bid % gx) * 128;

    const int sr  = lane >> 2;   // 0..15 row within 16-row chunk
    const int scb = lane & 3;    // lds col-block (8 shorts)

    f32x4 acc[4][4];
    #pragma unroll
    for (int mt = 0; mt < 4; ++mt)
        #pragma unroll
        for (int nt = 0; nt < 4; ++nt) acc[mt][nt] = (f32x4){0.f, 0.f, 0.f, 0.f};

    for (int k0 = 0; k0 < K; k0 += 32) {
        __syncthreads();
        #pragma unroll
        for (int i = 0; i < 2; ++i) {
            int rb = i * 64 + wave * 16;          // chunk base row (wave-uniform)
            int r  = rb + sr;
            int csrc = (scb ^ ((r >> 1) & 3)) * 8;
            gl_lds16(A  + (size_t)(brow + r) * K + k0 + csrc, &As[rb * 32]);
            gl_lds16(Bt + (size_t)(bcol + r) * K + k0 + csrc, &Bs[rb * 32]);
        }
        __syncthreads();

        bf16x8 af[4], bf[4];
        #pragma unroll
        for (int mt = 0; mt < 4; ++mt) {
            int r = wm + mt * 16 + ln16;
            af[mt] = *(const bf16x8*)&As[r * 32 + ((quad ^ ((r >> 1) & 3)) * 8)];
        }
        #pragma unroll
        for (int nt = 0; nt < 4; ++nt) {
            int r = wn + nt * 16 + ln16;
            bf[nt] = *(const bf16x8*)&Bs[r * 32 + ((quad ^ ((r >> 1) & 3)) * 8)];
        }
        #pragma unroll
        for (int mt = 0; mt < 4; ++mt)
            #pragma unroll
            for (int nt = 0; nt < 4; ++nt)
                acc[mt][nt] = __builtin_amdgcn_mfma_f32_16x16x32_bf16(
                    af[mt], bf[nt], acc[mt][nt], 0, 0, 0);
    }

    void* Cp = C0; int ld = ldc0; int coff = 0;
    if (bcol >= split_col) { Cp = C1; ld = ldc1; coff = split_col; }

    #pragma unroll
    for (int mt = 0; mt < 4; ++mt) {
        #pragma unroll
        for (int r = 0; r < 4; ++r) {
            int row = brow + wm + mt * 16 + quad * 4 + r;
            #pragma unroll
            for (int nt = 0; nt < 4; ++nt) {
                int col = bcol + wn + nt * 16 + ln16;
                float v = acc[mt][nt][r] + bias[col];
                if (resid) v += resid[(size_t)row * N + col];
                if (out_bf16) ((short*)Cp)[(size_t)row * ld + (col - coff)] = f2bf(v);
                else          ((float*)Cp)[(size_t)row * ld + (col - coff)] = v;
            }
        }
    }
}

// ---------------------------------------------------------------------------
// Vb[4096][1024] bf16 -> VT[1024][4096] bf16, 64x64 tiles
// ---------------------------------------------------------------------------
__global__ __launch_bounds__(256) void vtranspose_kernel(
    const short* __restrict__ Vb, short* __restrict__ VT)
{
    __shared__ short t[64][72];
    const int c0 = blockIdx.x * 64;    // feature block
    const int r0 = blockIdx.y * 64;    // token block
    const int tid = threadIdx.x;
    #pragma unroll
    for (int i = 0; i < 2; ++i) {
        int idx = tid + i * 256;
        int r = idx >> 3, cc = (idx & 7) * 8;
        *(uint4*)&t[r][cc] = *(const uint4*)(Vb + (size_t)(r0 + r) * 1024 + c0 + cc);
    }
    __syncthreads();
    #pragma unroll
    for (int i = 0; i < 2; ++i) {
        int idx = tid + i * 256;
        int c = idx >> 3, rr = (idx & 7) * 8;
        short tmp[8];
        #pragma unroll
        for (int j = 0; j < 8; ++j) tmp[j] = t[rr + j][c];
        *(uint4*)(VT + (size_t)(c0 + c) * 4096 + r0 + rr) = *(uint4*)tmp;
    }
}

// ---------------------------------------------------------------------------
// MFMA flash attention: k-split waves, minimal-state version.
// QKb[4096][2048]: Q cols 0..1023, K cols 1024..2047.  VT[1024][4096] = V^T.
// Block = (h, qt, b): 64 q-rows, 4 waves, 128-token k-tiles (16 iters).
// Wave w owns tokens [32w, 32w+32) for ALL 64 q-rows (k-split: K/V LDS
// reads are 1x, not 4x redundant).  Register-state diet vs prior rounds:
//   - rowsum via VALU accumulation of exp2 outputs (all 4 accum values of a
//     lane share one q-row in the S^T C-layout) -> no ones-MFMA, no lacc
//     AGPRs; quad-reduction deferred to the epilogue (2 shfl_xor).
//   - P buffer aliases the wave's own K quarter (both wave-private; all kf
//     fragments are hoisted into regs BEFORE any P write; DS pipe executes
//     a wave's LDS ops in order) -> LDS = 32 KB total.
// Single-buffered staging; __syncthreads' vmcnt drain is covered by
// cross-block TLP (3+ blocks/CU).  Fixed-max softmax (p = exp2(s)).
// ---------------------------------------------------------------------------
__global__ __launch_bounds__(256, 3) void attn_mfma_kernel(
    const short* __restrict__ QKb, const short* __restrict__ VT,
    short* __restrict__ Ctx)
{
    const int S = 2048;
    const int h = blockIdx.x, qt = blockIdx.y, b = blockIdx.z;
    const int tid = threadIdx.x;
    const int wave = tid >> 6, lane = tid & 63;
    const int ln16 = lane & 15, quad = lane >> 4;

    // LDS 32768 B:
    //   [0,16384)     Ks[128 tok][64 d]  rows 128 B, 16B-block key r&7
    //   [16384,32768) Vs[64 d][128 tok]  rows 256 B, 16B-block key d&15
    //   P[64 q][32 k] (4 KB/wave) aliases the wave's own K quarter.
    // epilogue overlays [0,20480): Rw[4][64][19] f32 + Lb[4][64] f32
    __shared__ alignas(16) char smem[32768];
    short* Ks = (short*)smem;
    short* Vs = (short*)(smem + 16384);
    char*  Pw = smem + wave * 4096;          // aliases Ks rows [32w,32w+32)

    // Q fragments for all 64 q-rows (B-operand), straight from global
    bf16x8 qf[4][2];
    #pragma unroll
    for (int qg = 0; qg < 4; ++qg)
        #pragma unroll
        for (int kb = 0; kb < 2; ++kb)
            qf[qg][kb] = *(const bf16x8*)(QKb +
                (size_t)(b * S + qt * 64 + qg * 16 + ln16) * 2048 +
                h * 64 + kb * 32 + quad * 8);

    f32x4 of[4][4];
    float rs[4] = {0.f, 0.f, 0.f, 0.f};
    #pragma unroll
    for (int qg = 0; qg < 4; ++qg)
        #pragma unroll
        for (int nt = 0; nt < 4; ++nt) of[qg][nt] = (f32x4){0.f, 0.f, 0.f, 0.f};

    // stage 128-token tile kt: 8 DMA per wave
    // (wave stages K rows [32w,32w+32) and V feature-rows [16w,16w+16))
    auto stage = [&](int kt) {
        const int kr  = lane >> 3;    // 0..7  row within 8-row K chunk
        const int kb8 = lane & 7;     // K 16B-block in 128-B row
        const int vr  = lane >> 4;    // 0..3  row within 4-row V chunk
        const int vb16 = lane & 15;   // V 16B-block in 256-B row
        #pragma unroll
        for (int i = 0; i < 4; ++i) {
            int r = wave * 32 + i * 8 + kr;               // tile token row
            int ksrc = (kb8 ^ (r & 7)) * 8;
            gl_lds16(QKb + (size_t)(b * S + kt * 128 + r) * 2048 + 1024 + h * 64 + ksrc,
                     Ks + (wave * 32 + i * 8) * 64);
            int d = wave * 16 + i * 4 + vr;               // feature row
            int vsrc = (vb16 ^ (d & 15)) * 8;
            gl_lds16(VT + (size_t)(h * 64 + d) * 4096 + b * S + kt * 128 + vsrc,
                     Vs + (wave * 16 + i * 4) * 128);
        }
    };

    for (int kt = 0; kt < 16; ++kt) {
        if (kt) __syncthreads();          // prev tile K/V/P reads done
        stage(kt);
        __syncthreads();                  // vmcnt drain + barrier: tile staged

        const int t0w = wave * 32;        // this wave's token window

        // ALL kf reads hoisted (P writes below clobber the wave's K quarter)
        bf16x8 kf[2][2];
        #pragma unroll
        for (int kblk = 0; kblk < 2; ++kblk) {
            int rloc = t0w + kblk * 16 + ln16;
            kf[kblk][0] = *(const bf16x8*)&Ks[rloc * 64 + ((quad ^ (rloc & 7)) * 8)];
            kf[kblk][1] = *(const bf16x8*)&Ks[rloc * 64 + (((4 + quad) ^ (rloc & 7)) * 8)];
        }

        // S^T = K Q^T ; exp2 ; VALU rowsum ; swizzled b64 P write (alias OK)
        #pragma unroll
        for (int kblk = 0; kblk < 2; ++kblk) {
            #pragma unroll
            for (int qg = 0; qg < 4; ++qg) {
                f32x4 a = (f32x4){0.f, 0.f, 0.f, 0.f};
                a = __builtin_amdgcn_mfma_f32_16x16x32_bf16(kf[kblk][0], qf[qg][0], a, 0, 0, 0);
                a = __builtin_amdgcn_mfma_f32_16x16x32_bf16(kf[kblk][1], qf[qg][1], a, 0, 0, 0);
                float p0 = EXP2(a[0]), p1 = EXP2(a[1]);
                float p2 = EXP2(a[2]), p3 = EXP2(a[3]);
                rs[qg] += (p0 + p1) + (p2 + p3);
                union { __hip_bfloat162 h2; unsigned u; } c01, c23;
                c01.h2 = __float22bfloat162_rn(make_float2(p0, p1));
                c23.h2 = __float22bfloat162_rn(make_float2(p2, p3));
                uint2 w; w.x = c01.u; w.y = c23.u;
                int qrow = qg * 16 + ln16;
                int key = (qrow >> 1) & 3;
                int bblk = (kblk * 2 + (quad >> 1)) ^ key;
                *(uint2*)(Pw + qrow * 64 + bblk * 16 + (quad & 1) * 8) = w;
            }
        }

        // P fragments back (wave-private: no barrier) + PV
        bf16x8 pf[4];
        #pragma unroll
        for (int qg = 0; qg < 4; ++qg) {
            int qrow = qg * 16 + ln16;
            int key = (qrow >> 1) & 3;
            pf[qg] = *(const bf16x8*)(Pw + qrow * 64 + ((quad ^ key) * 16));
        }
        #pragma unroll
        for (int nt = 0; nt < 4; ++nt) {
            int d = nt * 16 + ln16;
            bf16x8 vf = *(const bf16x8*)&Vs[d * 128 + (((wave * 4 + quad) ^ (d & 15)) * 8)];
            #pragma unroll
            for (int qg = 0; qg < 4; ++qg)
                of[qg][nt] = __builtin_amdgcn_mfma_f32_16x16x32_bf16(pf[qg], vf, of[qg][nt], 0, 0, 0);
        }
    }

    // ---- epilogue: cross-wave reduce of O partials and rowsums
    __syncthreads();                              // tiles dead; smem reused

    // rs currently holds this lane's tokens only; fold quads (lanes ^16, ^32)
    #pragma unroll
    for (int qg = 0; qg < 4; ++qg) {
        rs[qg] += __shfl_xor(rs[qg], 16, 64);
        rs[qg] += __shfl_xor(rs[qg], 32, 64);
    }

    float* Rw = (float*)(smem + wave * 4864);     // [64][19] f32, this wave
    float* Lb = (float*)(smem + 4 * 4864);        // [4][64] rowsum partials

    if (quad == 0) {
        #pragma unroll
        for (int qg = 0; qg < 4; ++qg)
            Lb[wave * 64 + qg * 16 + ln16] = rs[qg];
    }

    const int rq  = tid >> 2;          // 0..63: q-row this thread reduces
    const int rd0 = (tid & 3) * 4;     // 4 d-cols per thread
    float inv = 0.f;

    #pragma unroll
    for (int nt = 0; nt < 4; ++nt) {
        #pragma unroll
        for (int qg = 0; qg < 4; ++qg)
            #pragma unroll
            for (int r = 0; r < 4; ++r)
                Rw[(qg * 16 + quad * 4 + r) * 19 + ln16] = of[qg][nt][r];
        __syncthreads();
        if (nt == 0) {
            float l = Lb[rq] + Lb[64 + rq] + Lb[128 + rq] + Lb[192 + rq];
            inv = 1.f / l;
        }
        short o4[4];
        #pragma unroll
        for (int j = 0; j < 4; ++j) {
            int d = rd0 + j;
            float s = 0.f;
            #pragma unroll
            for (int w = 0; w < 4; ++w)
                s += ((const float*)(smem + w * 4864))[rq * 19 + d];
            o4[j] = f2bf(s * inv);
        }
        *(uint2*)(Ctx + (size_t)(b * S + qt * 64 + rq) * 1024 + h * 64 + nt * 16 + rd0) =
            *(uint2*)o4;
        __syncthreads();
    }
}

// ---------------------------------------------------------------------------
// out = LayerNorm(x) * gamma + beta (residual already folded into x).
// One block per row; exactly one float4 per thread.
// ---------------------------------------------------------------------------
__global__ __launch_bounds__(256) void resln_kernel(
    const float* __restrict__ xin, const float* __restrict__ gamma,
    const float* __restrict__ beta, float* __restrict__ out)
{
    const int row = blockIdx.x;
    const int tid = threadIdx.x;
    const int wid = tid >> 6, lane = tid & 63;
    __shared__ float red[8];

    float4 x = *(const float4*)(xin + (size_t)row * HIDDEN + tid * 4);
    float s = x.x + x.y + x.z + x.w;
    #pragma unroll
    for (int off = 32; off > 0; off >>= 1) s += __shfl_xor(s, off, 64);
    if (lane == 0) red[wid] = s;
    __syncthreads();
    float mu = (red[0] + red[1] + red[2] + red[3]) * (1.f / HIDDEN);

    float dx = x.x - mu, dy = x.y - mu, dz = x.z - mu, dw = x.w - mu;
    float v = dx * dx + dy * dy + dz * dz + dw * dw;
    #pragma unroll
    for (int off = 32; off > 0; off >>= 1) v += __shfl_xor(v, off, 64);
    if (lane == 0) red[4 + wid] = v;
    __syncthreads();
    float var = (red[4] + red[5] + red[6] + red[7]) * (1.f / HIDDEN);
    float rstd = rsqrtf(var + EPS);

    float4 g = *(const float4*)(gamma + tid * 4);
    float4 bt = *(const float4*)(beta + tid * 4);
    float4 o;
    o.x = dx * rstd * g.x + bt.x;
    o.y = dy * rstd * g.y + bt.y;
    o.z = dz * rstd * g.z + bt.z;
    o.w = dw * rstd * g.w + bt.w;
    *(float4*)(out + (size_t)row * HIDDEN + tid * 4) = o;
}

// ---------------------------------------------------------------------------
extern "C" void kernel_launch(void* const* d_in, const int* in_sizes, int n_in,
                              void* d_out, int out_size, void* d_ws, size_t ws_size,
                              hipStream_t stream)
{
    const float* X     = (const float*)d_in[0];
    const float* Wq    = (const float*)d_in[1];
    const float* bq    = (const float*)d_in[2];
    const float* Wk    = (const float*)d_in[3];
    const float* bk    = (const float*)d_in[4];
    const float* Wv    = (const float*)d_in[5];
    const float* bv    = (const float*)d_in[6];
    const float* Wo    = (const float*)d_in[7];
    const float* bo    = (const float*)d_in[8];
    const float* gamma = (const float*)d_in[9];
    const float* beta  = (const float*)d_in[10];
    float* out = (float*)d_out;

    const int B = 2, S = 2048;
    const int M = B * S;                       // 4096
    const size_t mat = (size_t)M * HIDDEN;     // 4M elems

    // workspace map (peak 41 MB):
    //   [0,8)    Xb (dead after QKV gemm) -> VT overlays
    //   [8,10)   Wot
    //   [10,16)  Wt3 (3072x1024 bf16)
    //   [16,17)  b3
    //   [17,33)  QKb (dead after attn) -> Pj (fp32) overlays
    //   [33,41)  Vb (dead after vtrans) -> Ctx overlays
    char* ws = (char*)d_ws;
    short* Xb  = (short*)(ws);
    short* VT  = (short*)(ws);
    short* Wot = (short*)(ws + (8ull << 20));
    short* Wt3 = (short*)(ws + (10ull << 20));
    float* b3  = (float*)(ws + (16ull << 20));
    short* QKb = (short*)(ws + (17ull << 20));
    float* Pj  = (float*)(ws + (17ull << 20));
    short* Vb  = (short*)(ws + (33ull << 20));
    short* Ctx = (short*)(ws + (33ull << 20));

    dim3 blk(256);

    cast_bf16_kernel<<<dim3((int)(mat / 4 / 256)), blk, 0, stream>>>(X, Xb, (int)mat);
    wtrans_kernel<<<dim3(32, 32, 4), blk, 0, stream>>>(Wq, Wk, Wv, Wo, Wt3, Wot);
    concat_bias_kernel<<<12, blk, 0, stream>>>(bq, bk, bv, b3);

    // fused QKV projection: N=3072, V columns routed to Vb
    dim3 qkvgrid(3072 / 128, M / 128);         // (24, 32) = 768 blocks
    gemm_bt_mfma<<<qkvgrid, blk, 0, stream>>>(Xb, Wt3, b3,
                                              QKb, 2048, Vb, 2048, 1024,
                                              nullptr, M, 3072, HIDDEN, 1);

    vtranspose_kernel<<<dim3(16, 64), blk, 0, stream>>>(Vb, VT);

    dim3 agrid(HEADS, S / 64, B);              // (16, 32, 2) = 1024 blocks
    attn_mfma_kernel<<<agrid, blk, 0, stream>>>(QKb, VT, Ctx);

    // output projection + bias + residual (fp32 out)
    dim3 ogrid(HIDDEN / 128, M / 128);         // (8, 32)
    gemm_bt_mfma<<<ogrid, blk, 0, stream>>>(Ctx, Wot, bo,
                                            Pj, 1024, nullptr, 1 << 30, 0,
                                            X, M, HIDDEN, HIDDEN, 0);

    resln_kernel<<<M, blk, 0, stream>>>(Pj, gamma, beta, out);
}

// Round 5
// 231.382 us; speedup vs baseline: 1.1295x; 1.0720x over previous
//
#include <hip/hip_runtime.h>
#include <hip/hip_bf16.h>
#include <math.h>

#define HIDDEN 1024
#define HEADS 16
#define HEAD_DIM 64
#define EPS 1e-5f

typedef __attribute__((ext_vector_type(8))) short bf16x8;
typedef __attribute__((ext_vector_type(4))) float f32x4;

#if defined(__has_builtin)
#if __has_builtin(__builtin_amdgcn_exp2f)
#define EXP2(x) __builtin_amdgcn_exp2f(x)
#endif
#endif
#ifndef EXP2
#define EXP2(x) exp2f(x)
#endif

// 0.125 (1/sqrt(64)) * log2(e): folded into Wq/bq so softmax is exp2(s)
#define QSCALE 0.18033688011112042f

__device__ __forceinline__ short f2bf(float f) {
    union { float f; unsigned u; } v; v.f = f;
    unsigned r = v.u + 0x7fffu + ((v.u >> 16) & 1u);   // RNE
    return (short)(r >> 16);
}

// async global->LDS DMA, 16 B per lane; dest = ldsbase + lane*16 (wave-uniform base)
__device__ __forceinline__ void gl_lds16(const void* g, void* l) {
    __builtin_amdgcn_global_load_lds(
        (const __attribute__((address_space(1))) void*)g,
        (__attribute__((address_space(3))) void*)l, 16, 0, 0);
}

// ---------------------------------------------------------------------------
// fp32 -> bf16 cast, 4 elems/thread
// ---------------------------------------------------------------------------
__global__ __launch_bounds__(256) void cast_bf16_kernel(
    const float* __restrict__ in, short* __restrict__ out, int n)
{
    int i = (blockIdx.x * 256 + threadIdx.x) * 4;
    if (i >= n) return;
    float4 v = *(const float4*)(in + i);
    short o[4] = { f2bf(v.x), f2bf(v.y), f2bf(v.z), f2bf(v.w) };
    *(uint2*)(out + i) = *(uint2*)o;
}

// ---------------------------------------------------------------------------
// All 4 weights: W[K,N] fp32 -> Wt[N,K] bf16 (32x32 tiles), z picks weight
// ---------------------------------------------------------------------------
__global__ __launch_bounds__(256) void wtrans_kernel(
    const float* __restrict__ Wq, const float* __restrict__ Wk,
    const float* __restrict__ Wv, const float* __restrict__ Wo,
    short* __restrict__ Wt3, short* __restrict__ Wot)
{
    const int wsel = blockIdx.z;
    const float* W = (wsel == 0) ? Wq : (wsel == 1) ? Wk : (wsel == 2) ? Wv : Wo;
    short* dst = (wsel < 3) ? (Wt3 + (size_t)wsel * 1024 * 1024) : Wot;
    const float scale = (wsel == 0) ? QSCALE : 1.0f;

    __shared__ short tile[32][33];
    int n0 = blockIdx.x * 32;
    int k0 = blockIdx.y * 32;
    int tx = threadIdx.x & 31;
    int ty = threadIdx.x >> 5;  // 0..7
    #pragma unroll
    for (int i = 0; i < 32; i += 8)
        tile[ty + i][tx] = f2bf(W[(size_t)(k0 + ty + i) * 1024 + n0 + tx] * scale);
    __syncthreads();
    #pragma unroll
    for (int i = 0; i < 32; i += 8)
        dst[(size_t)(n0 + ty + i) * 1024 + k0 + tx] = tile[tx][ty + i];
}

// ---------------------------------------------------------------------------
// b3 = concat(bq*qscale, bk, bv)
// ---------------------------------------------------------------------------
__global__ __launch_bounds__(256) void concat_bias_kernel(
    const float* __restrict__ bq, const float* __restrict__ bk,
    const float* __restrict__ bv, float* __restrict__ b3)
{
    int i = blockIdx.x * 256 + threadIdx.x;
    if (i >= 3072) return;
    float v = (i < 1024) ? bq[i] * QSCALE
            : (i < 2048) ? bk[i - 1024] : bv[i - 2048];
    b3[i] = v;
}

// ---------------------------------------------------------------------------
// C[M,N] = A[M,K] @ Bt[N,K]^T + bias[col] (+ resid fp32 if given).
// BM x 128 tile (BM = 128 or 64), BK=64, 4 waves.  BK=64 halves the
// barrier-drain count vs BK=32 (the dominant stall of the 2-phase loop).
// Staging via global_load_lds (16B DMA) with the attn-proven row layout:
// 128-B rows, 16B-block XOR key r&7, fragment read block (kk*4+quad)^(r&7).
// Accumulation order identical to two BK=32 steps -> bitwise-same output.
// Columns >= split_col go to C1 (rebased), else C0.  Bijective XCD swizzle
// (nwg%8==0 at all call sites) keeps neighbor tiles on one XCD's L2.
// ---------------------------------------------------------------------------
template<int BM>
__global__ __launch_bounds__(256) void gemm_bt_mfma(
    const short* __restrict__ A, const short* __restrict__ Bt,
    const float* __restrict__ bias,
    void* __restrict__ C0, int ldc0,
    void* __restrict__ C1, int split_col, int ldc1,
    const float* __restrict__ resid,
    int M, int N, int K, int out_bf16)
{
    constexpr int MT = BM / 32;          // m-tiles per wave (4 or 2)
    constexpr int ACH = BM / 32;         // A 8-row chunks per wave
    __shared__ short As[BM * 64];
    __shared__ short Bs[128 * 64];
    const int tid = threadIdx.x;
    const int wave = tid >> 6, lane = tid & 63;
    const int ln16 = lane & 15, quad = lane >> 4;
    const int wm = (wave >> 1) * (BM / 2), wn = (wave & 1) * 64;

    const int gx = gridDim.x;
    int bid = blockIdx.y * gx + blockIdx.x;
    const int cpx = (gx * gridDim.y) >> 3;     // nwg/8, exact at all call sites
    bid = (bid & 7) * cpx + (bid >> 3);        // XCD-contiguous logical tiles
    const int brow = (bid / gx) * BM, bcol = (bid % gx) * 128;

    const int kr  = lane >> 3;   // 0..7 row within 8-row chunk
    const int kb8 = lane & 7;    // 16B block within 128-B row

    f32x4 acc[MT][4];
    #pragma unroll
    for (int mt = 0; mt < MT; ++mt)
        #pragma unroll
        for (int nt = 0; nt < 4; ++nt) acc[mt][nt] = (f32x4){0.f, 0.f, 0.f, 0.f};

    for (int k0 = 0; k0 < K; k0 += 64) {
        __syncthreads();
        #pragma unroll
        for (int i = 0; i < ACH; ++i) {
            int ci = wave * ACH + i;
            int r  = ci * 8 + kr;
            int csrc = (kb8 ^ (r & 7)) * 8;
            gl_lds16(A + (size_t)(brow + r) * K + k0 + csrc, As + ci * 512);
        }
        #pragma unroll
        for (int i = 0; i < 4; ++i) {
            int ci = wave * 4 + i;
            int r  = ci * 8 + kr;
            int csrc = (kb8 ^ (r & 7)) * 8;
            gl_lds16(Bt + (size_t)(bcol + r) * K + k0 + csrc, Bs + ci * 512);
        }
        __syncthreads();

        #pragma unroll
        for (int kk = 0; kk < 2; ++kk) {
            bf16x8 af[MT], bf[4];
            #pragma unroll
            for (int mt = 0; mt < MT; ++mt) {
                int r = wm + mt * 16 + ln16;
                af[mt] = *(const bf16x8*)&As[r * 64 + (((kk * 4 + quad) ^ (r & 7)) * 8)];
            }
            #pragma unroll
            for (int nt = 0; nt < 4; ++nt) {
                int r = wn + nt * 16 + ln16;
                bf[nt] = *(const bf16x8*)&Bs[r * 64 + (((kk * 4 + quad) ^ (r & 7)) * 8)];
            }
            #pragma unroll
            for (int mt = 0; mt < MT; ++mt)
                #pragma unroll
                for (int nt = 0; nt < 4; ++nt)
                    acc[mt][nt] = __builtin_amdgcn_mfma_f32_16x16x32_bf16(
                        af[mt], bf[nt], acc[mt][nt], 0, 0, 0);
        }
    }

    void* Cp = C0; int ld = ldc0; int coff = 0;
    if (bcol >= split_col) { Cp = C1; ld = ldc1; coff = split_col; }

    #pragma unroll
    for (int mt = 0; mt < MT; ++mt) {
        #pragma unroll
        for (int r = 0; r < 4; ++r) {
            int row = brow + wm + mt * 16 + quad * 4 + r;
            #pragma unroll
            for (int nt = 0; nt < 4; ++nt) {
                int col = bcol + wn + nt * 16 + ln16;
                float v = acc[mt][nt][r] + bias[col];
                if (resid) v += resid[(size_t)row * N + col];
                if (out_bf16) ((short*)Cp)[(size_t)row * ld + (col - coff)] = f2bf(v);
                else          ((float*)Cp)[(size_t)row * ld + (col - coff)] = v;
            }
        }
    }
}

// ---------------------------------------------------------------------------
// Vb[4096][1024] bf16 -> VT[1024][4096] bf16, 64x64 tiles
// ---------------------------------------------------------------------------
__global__ __launch_bounds__(256) void vtranspose_kernel(
    const short* __restrict__ Vb, short* __restrict__ VT)
{
    __shared__ short t[64][72];
    const int c0 = blockIdx.x * 64;    // feature block
    const int r0 = blockIdx.y * 64;    // token block
    const int tid = threadIdx.x;
    #pragma unroll
    for (int i = 0; i < 2; ++i) {
        int idx = tid + i * 256;
        int r = idx >> 3, cc = (idx & 7) * 8;
        *(uint4*)&t[r][cc] = *(const uint4*)(Vb + (size_t)(r0 + r) * 1024 + c0 + cc);
    }
    __syncthreads();
    #pragma unroll
    for (int i = 0; i < 2; ++i) {
        int idx = tid + i * 256;
        int c = idx >> 3, rr = (idx & 7) * 8;
        short tmp[8];
        #pragma unroll
        for (int j = 0; j < 8; ++j) tmp[j] = t[rr + j][c];
        *(uint4*)(VT + (size_t)(c0 + c) * 4096 + r0 + rr) = *(uint4*)tmp;
    }
}

// ---------------------------------------------------------------------------
// MFMA flash attention: k-split waves, minimal-state version (R4 structure)
// + s_setprio(1) around MFMA clusters (T5: cross-block role diversity at
// 4 blocks/CU lets the CU scheduler favor MFMA-issuing waves).
// ---------------------------------------------------------------------------
__global__ __launch_bounds__(256, 3) void attn_mfma_kernel(
    const short* __restrict__ QKb, const short* __restrict__ VT,
    short* __restrict__ Ctx)
{
    const int S = 2048;
    const int h = blockIdx.x, qt = blockIdx.y, b = blockIdx.z;
    const int tid = threadIdx.x;
    const int wave = tid >> 6, lane = tid & 63;
    const int ln16 = lane & 15, quad = lane >> 4;

    // LDS 32768 B:
    //   [0,16384)     Ks[128 tok][64 d]  rows 128 B, 16B-block key r&7
    //   [16384,32768) Vs[64 d][128 tok]  rows 256 B, 16B-block key d&15
    //   P[64 q][32 k] (4 KB/wave) aliases the wave's own K quarter.
    // epilogue overlays [0,20480): Rw[4][64][19] f32 + Lb[4][64] f32
    __shared__ alignas(16) char smem[32768];
    short* Ks = (short*)smem;
    short* Vs = (short*)(smem + 16384);
    char*  Pw = smem + wave * 4096;          // aliases Ks rows [32w,32w+32)

    // Q fragments for all 64 q-rows (B-operand), straight from global
    bf16x8 qf[4][2];
    #pragma unroll
    for (int qg = 0; qg < 4; ++qg)
        #pragma unroll
        for (int kb = 0; kb < 2; ++kb)
            qf[qg][kb] = *(const bf16x8*)(QKb +
                (size_t)(b * S + qt * 64 + qg * 16 + ln16) * 2048 +
                h * 64 + kb * 32 + quad * 8);

    f32x4 of[4][4];
    float rs[4] = {0.f, 0.f, 0.f, 0.f};
    #pragma unroll
    for (int qg = 0; qg < 4; ++qg)
        #pragma unroll
        for (int nt = 0; nt < 4; ++nt) of[qg][nt] = (f32x4){0.f, 0.f, 0.f, 0.f};

    // stage 128-token tile kt: 8 DMA per wave
    // (wave stages K rows [32w,32w+32) and V feature-rows [16w,16w+16))
    auto stage = [&](int kt) {
        const int kr  = lane >> 3;    // 0..7  row within 8-row K chunk
        const int kb8 = lane & 7;     // K 16B-block in 128-B row
        const int vr  = lane >> 4;    // 0..3  row within 4-row V chunk
        const int vb16 = lane & 15;   // V 16B-block in 256-B row
        #pragma unroll
        for (int i = 0; i < 4; ++i) {
            int r = wave * 32 + i * 8 + kr;               // tile token row
            int ksrc = (kb8 ^ (r & 7)) * 8;
            gl_lds16(QKb + (size_t)(b * S + kt * 128 + r) * 2048 + 1024 + h * 64 + ksrc,
                     Ks + (wave * 32 + i * 8) * 64);
            int d = wave * 16 + i * 4 + vr;               // feature row
            int vsrc = (vb16 ^ (d & 15)) * 8;
            gl_lds16(VT + (size_t)(h * 64 + d) * 4096 + b * S + kt * 128 + vsrc,
                     Vs + (wave * 16 + i * 4) * 128);
        }
    };

    for (int kt = 0; kt < 16; ++kt) {
        if (kt) __syncthreads();          // prev tile K/V/P reads done
        stage(kt);
        __syncthreads();                  // vmcnt drain + barrier: tile staged

        const int t0w = wave * 32;        // this wave's token window

        // ALL kf reads hoisted (P writes below clobber the wave's K quarter)
        bf16x8 kf[2][2];
        #pragma unroll
        for (int kblk = 0; kblk < 2; ++kblk) {
            int rloc = t0w + kblk * 16 + ln16;
            kf[kblk][0] = *(const bf16x8*)&Ks[rloc * 64 + ((quad ^ (rloc & 7)) * 8)];
            kf[kblk][1] = *(const bf16x8*)&Ks[rloc * 64 + (((4 + quad) ^ (rloc & 7)) * 8)];
        }

        // S^T = K Q^T ; exp2 ; VALU rowsum ; swizzled b64 P write (alias OK)
        #pragma unroll
        for (int kblk = 0; kblk < 2; ++kblk) {
            #pragma unroll
            for (int qg = 0; qg < 4; ++qg) {
                f32x4 a = (f32x4){0.f, 0.f, 0.f, 0.f};
                __builtin_amdgcn_s_setprio(1);
                a = __builtin_amdgcn_mfma_f32_16x16x32_bf16(kf[kblk][0], qf[qg][0], a, 0, 0, 0);
                a = __builtin_amdgcn_mfma_f32_16x16x32_bf16(kf[kblk][1], qf[qg][1], a, 0, 0, 0);
                __builtin_amdgcn_s_setprio(0);
                float p0 = EXP2(a[0]), p1 = EXP2(a[1]);
                float p2 = EXP2(a[2]), p3 = EXP2(a[3]);
                rs[qg] += (p0 + p1) + (p2 + p3);
                union { __hip_bfloat162 h2; unsigned u; } c01, c23;
                c01.h2 = __float22bfloat162_rn(make_float2(p0, p1));
                c23.h2 = __float22bfloat162_rn(make_float2(p2, p3));
                uint2 w; w.x = c01.u; w.y = c23.u;
                int qrow = qg * 16 + ln16;
                int key = (qrow >> 1) & 3;
                int bblk = (kblk * 2 + (quad >> 1)) ^ key;
                *(uint2*)(Pw + qrow * 64 + bblk * 16 + (quad & 1) * 8) = w;
            }
        }

        // P fragments back (wave-private: no barrier) + PV
        bf16x8 pf[4];
        #pragma unroll
        for (int qg = 0; qg < 4; ++qg) {
            int qrow = qg * 16 + ln16;
            int key = (qrow >> 1) & 3;
            pf[qg] = *(const bf16x8*)(Pw + qrow * 64 + ((quad ^ key) * 16));
        }
        __builtin_amdgcn_s_setprio(1);
        #pragma unroll
        for (int nt = 0; nt < 4; ++nt) {
            int d = nt * 16 + ln16;
            bf16x8 vf = *(const bf16x8*)&Vs[d * 128 + (((wave * 4 + quad) ^ (d & 15)) * 8)];
            #pragma unroll
            for (int qg = 0; qg < 4; ++qg)
                of[qg][nt] = __builtin_amdgcn_mfma_f32_16x16x32_bf16(pf[qg], vf, of[qg][nt], 0, 0, 0);
        }
        __builtin_amdgcn_s_setprio(0);
    }

    // ---- epilogue: cross-wave reduce of O partials and rowsums
    __syncthreads();                              // tiles dead; smem reused

    // rs currently holds this lane's tokens only; fold quads (lanes ^16, ^32)
    #pragma unroll
    for (int qg = 0; qg < 4; ++qg) {
        rs[qg] += __shfl_xor(rs[qg], 16, 64);
        rs[qg] += __shfl_xor(rs[qg], 32, 64);
    }

    float* Rw = (float*)(smem + wave * 4864);     // [64][19] f32, this wave
    float* Lb = (float*)(smem + 4 * 4864);        // [4][64] rowsum partials

    if (quad == 0) {
        #pragma unroll
        for (int qg = 0; qg < 4; ++qg)
            Lb[wave * 64 + qg * 16 + ln16] = rs[qg];
    }

    const int rq  = tid >> 2;          // 0..63: q-row this thread reduces
    const int rd0 = (tid & 3) * 4;     // 4 d-cols per thread
    float inv = 0.f;

    #pragma unroll
    for (int nt = 0; nt < 4; ++nt) {
        #pragma unroll
        for (int qg = 0; qg < 4; ++qg)
            #pragma unroll
            for (int r = 0; r < 4; ++r)
                Rw[(qg * 16 + quad * 4 + r) * 19 + ln16] = of[qg][nt][r];
        __syncthreads();
        if (nt == 0) {
            float l = Lb[rq] + Lb[64 + rq] + Lb[128 + rq] + Lb[192 + rq];
            inv = 1.f / l;
        }
        short o4[4];
        #pragma unroll
        for (int j = 0; j < 4; ++j) {
            int d = rd0 + j;
            float s = 0.f;
            #pragma unroll
            for (int w = 0; w < 4; ++w)
                s += ((const float*)(smem + w * 4864))[rq * 19 + d];
            o4[j] = f2bf(s * inv);
        }
        *(uint2*)(Ctx + (size_t)(b * S + qt * 64 + rq) * 1024 + h * 64 + nt * 16 + rd0) =
            *(uint2*)o4;
        __syncthreads();
    }
}

// ---------------------------------------------------------------------------
// out = LayerNorm(x) * gamma + beta (residual already folded into x).
// One block per row; exactly one float4 per thread.
// ---------------------------------------------------------------------------
__global__ __launch_bounds__(256) void resln_kernel(
    const float* __restrict__ xin, const float* __restrict__ gamma,
    const float* __restrict__ beta, float* __restrict__ out)
{
    const int row = blockIdx.x;
    const int tid = threadIdx.x;
    const int wid = tid >> 6, lane = tid & 63;
    __shared__ float red[8];

    float4 x = *(const float4*)(xin + (size_t)row * HIDDEN + tid * 4);
    float s = x.x + x.y + x.z + x.w;
    #pragma unroll
    for (int off = 32; off > 0; off >>= 1) s += __shfl_xor(s, off, 64);
    if (lane == 0) red[wid] = s;
    __syncthreads();
    float mu = (red[0] + red[1] + red[2] + red[3]) * (1.f / HIDDEN);

    float dx = x.x - mu, dy = x.y - mu, dz = x.z - mu, dw = x.w - mu;
    float v = dx * dx + dy * dy + dz * dz + dw * dw;
    #pragma unroll
    for (int off = 32; off > 0; off >>= 1) v += __shfl_xor(v, off, 64);
    if (lane == 0) red[4 + wid] = v;
    __syncthreads();
    float var = (red[4] + red[5] + red[6] + red[7]) * (1.f / HIDDEN);
    float rstd = rsqrtf(var + EPS);

    float4 g = *(const float4*)(gamma + tid * 4);
    float4 bt = *(const float4*)(beta + tid * 4);
    float4 o;
    o.x = dx * rstd * g.x + bt.x;
    o.y = dy * rstd * g.y + bt.y;
    o.z = dz * rstd * g.z + bt.z;
    o.w = dw * rstd * g.w + bt.w;
    *(float4*)(out + (size_t)row * HIDDEN + tid * 4) = o;
}

// ---------------------------------------------------------------------------
extern "C" void kernel_launch(void* const* d_in, const int* in_sizes, int n_in,
                              void* d_out, int out_size, void* d_ws, size_t ws_size,
                              hipStream_t stream)
{
    const float* X     = (const float*)d_in[0];
    const float* Wq    = (const float*)d_in[1];
    const float* bq    = (const float*)d_in[2];
    const float* Wk    = (const float*)d_in[3];
    const float* bk    = (const float*)d_in[4];
    const float* Wv    = (const float*)d_in[5];
    const float* bv    = (const float*)d_in[6];
    const float* Wo    = (const float*)d_in[7];
    const float* bo    = (const float*)d_in[8];
    const float* gamma = (const float*)d_in[9];
    const float* beta  = (const float*)d_in[10];
    float* out = (float*)d_out;

    const int B = 2, S = 2048;
    const int M = B * S;                       // 4096
    const size_t mat = (size_t)M * HIDDEN;     // 4M elems

    // workspace map (peak 41 MB):
    //   [0,8)    Xb (dead after QKV gemm) -> VT overlays
    //   [8,10)   Wot
    //   [10,16)  Wt3 (3072x1024 bf16)
    //   [16,17)  b3
    //   [17,33)  QKb (dead after attn) -> Pj (fp32) overlays
    //   [33,41)  Vb (dead after vtrans) -> Ctx overlays
    char* ws = (char*)d_ws;
    short* Xb  = (short*)(ws);
    short* VT  = (short*)(ws);
    short* Wot = (short*)(ws + (8ull << 20));
    short* Wt3 = (short*)(ws + (10ull << 20));
    float* b3  = (float*)(ws + (16ull << 20));
    short* QKb = (short*)(ws + (17ull << 20));
    float* Pj  = (float*)(ws + (17ull << 20));
    short* Vb  = (short*)(ws + (33ull << 20));
    short* Ctx = (short*)(ws + (33ull << 20));

    dim3 blk(256);

    cast_bf16_kernel<<<dim3((int)(mat / 4 / 256)), blk, 0, stream>>>(X, Xb, (int)mat);
    wtrans_kernel<<<dim3(32, 32, 4), blk, 0, stream>>>(Wq, Wk, Wv, Wo, Wt3, Wot);
    concat_bias_kernel<<<12, blk, 0, stream>>>(bq, bk, bv, b3);

    // fused QKV projection: N=3072, V columns routed to Vb
    dim3 qkvgrid(3072 / 128, M / 128);         // (24, 32) = 768 blocks
    gemm_bt_mfma<128><<<qkvgrid, blk, 0, stream>>>(Xb, Wt3, b3,
                                              QKb, 2048, Vb, 2048, 1024,
                                              nullptr, M, 3072, HIDDEN, 1);

    vtranspose_kernel<<<dim3(16, 64), blk, 0, stream>>>(Vb, VT);

    dim3 agrid(HEADS, S / 64, B);              // (16, 32, 2) = 1024 blocks
    attn_mfma_kernel<<<agrid, blk, 0, stream>>>(QKb, VT, Ctx);

    // output projection + bias + residual (fp32 out); BM=64 -> 512 blocks
    dim3 ogrid(HIDDEN / 128, M / 64);          // (8, 64) = 512 blocks = 2/CU
    gemm_bt_mfma<64><<<ogrid, blk, 0, stream>>>(Ctx, Wot, bo,
                                            Pj, 1024, nullptr, 1 << 30, 0,
                                            X, M, HIDDEN, HIDDEN, 0);

    resln_kernel<<<M, blk, 0, stream>>>(Pj, gamma, beta, out);
}